// Round 9
// baseline (560.692 us; speedup 1.0000x reference)
//
#include <hip/hip_runtime.h>
#include <hip/hip_bf16.h>
#include <stdint.h>

// LSTM cell: gates = [X|h0](16384x2048) @ Bt^T(2048x4096), fused epilogue.
// R7: OCCUPANCY round. Five schedule variants (R1/R2/R4/R6) all measured the
// serial sum of LDS-read + MFMA at 1 block/CU (43-46.6% MfmaUtil): with
// 2 waves/SIMD there is no independent stream to hide either pipe. Trade
// tile for TLP: 256x128 tile, per-wave 64x64 (acc 64 VGPR), 2-slot BK=32
// LDS = 48 KiB, __launch_bounds__(512,4) -> 2 blocks/CU. m97-style loop
// {stage(t+1) -> 8 ds_reads -> 16 MFMA -> __syncthreads}; the per-tile
// vmcnt(0) drain is covered by the co-resident block (m114 mechanism).
// Gate-interleaved p-space: acc[mi][0..3] = gates i,f,g,o of ONE output
// column in the SAME lane -> epilogue is pure register math.

typedef __bf16 bf16x8 __attribute__((ext_vector_type(8)));
typedef float f32x4 __attribute__((ext_vector_type(4)));

#define B_ROWS 16384
#define KDIM 2048
#define DH 1024
#define HC_ELEMS 16777216ull  // 16384*1024
#define NT 64                 // K-tiles of BK=32
#define SLOT_BYTES 24576      // A 16K + B 8K per slot

__device__ __forceinline__ unsigned short f2bf(float f) {
  unsigned u = __float_as_uint(f);
  u = (u + 0x7fffu + ((u >> 16) & 1u)) >> 16;  // RNE
  return (unsigned short)u;
}

__device__ __forceinline__ float fsig(float x) {
  return __builtin_amdgcn_rcpf(1.0f + __expf(-x));
}
__device__ __forceinline__ float ftanh_(float x) {
  return 2.0f * __builtin_amdgcn_rcpf(1.0f + __expf(-2.0f * x)) - 1.0f;
}

// Fused prep: one kernel, three block ranges (unchanged, proven).
//  b in [0,8192):      A[m][k] = k<1024 ? X : h0, bf16, 16 elems/thread
//  b in [8192,9216):   Bt[n][1024+k'] = W[n][k'], bf16, 16 elems/thread
//  b in [9216,13312):  Bt[n][k] = U[k][n] (k<1024), 32x32 LDS transpose
__global__ void prep(const float* __restrict__ X, const float* __restrict__ h0,
                     const float* __restrict__ W, const float* __restrict__ U,
                     unsigned short* __restrict__ A, unsigned short* __restrict__ Bt) {
  __shared__ float tile[32][33];
  int b = blockIdx.x;
  if (b < 9216) {
    const float* src;
    unsigned short* dst;
    if (b < 8192) {
      size_t idx = ((size_t)b * 256 + threadIdx.x) * 16;
      int m = (int)(idx >> 11);
      int k = (int)(idx & 2047);
      src = (k < 1024) ? (X + (size_t)m * 1024 + k)
                       : (h0 + (size_t)m * 1024 + (k - 1024));
      dst = A + idx;
    } else {
      size_t idx = ((size_t)(b - 8192) * 256 + threadIdx.x) * 16;  // over 4096*1024
      int n = (int)(idx >> 10);
      int k = (int)(idx & 1023);
      src = W + (size_t)n * 1024 + k;
      dst = Bt + (size_t)n * 2048 + 1024 + k;
    }
    float4 a = ((const float4*)src)[0];
    float4 bb = ((const float4*)src)[1];
    float4 c = ((const float4*)src)[2];
    float4 d = ((const float4*)src)[3];
    union { unsigned short u[16]; uint4 v[2]; } pk;
    pk.u[0] = f2bf(a.x); pk.u[1] = f2bf(a.y); pk.u[2] = f2bf(a.z); pk.u[3] = f2bf(a.w);
    pk.u[4] = f2bf(bb.x); pk.u[5] = f2bf(bb.y); pk.u[6] = f2bf(bb.z); pk.u[7] = f2bf(bb.w);
    pk.u[8]  = f2bf(c.x); pk.u[9]  = f2bf(c.y); pk.u[10] = f2bf(c.z); pk.u[11] = f2bf(c.w);
    pk.u[12] = f2bf(d.x); pk.u[13] = f2bf(d.y); pk.u[14] = f2bf(d.z); pk.u[15] = f2bf(d.w);
    *(uint4*)(dst) = pk.v[0];
    *(uint4*)(dst + 8) = pk.v[1];
  } else {
    int bb = b - 9216;                    // 4096 blocks: 128 n-tiles x 32 k-tiles
    int n0 = (bb & 127) * 32;
    int k0 = (bb >> 7) * 32;
    int tx = threadIdx.x & 31, ty = threadIdx.x >> 5;  // ty in [0,8)
    #pragma unroll
    for (int i = 0; i < 4; ++i)
      tile[ty + i * 8][tx] = U[(size_t)(k0 + ty + i * 8) * 4096 + n0 + tx];
    __syncthreads();
    int nrel = threadIdx.x >> 3;          // 0..31
    int kc = (threadIdx.x & 7) * 4;       // 0..28
    union { unsigned short u[4]; uint2 v8; } pk;
    #pragma unroll
    for (int i = 0; i < 4; ++i) pk.u[i] = f2bf(tile[kc + i][nrel]);
    *(uint2*)(Bt + (size_t)(n0 + nrel) * 2048 + k0 + kc) = pk.v8;
  }
}

// GEMM + fused LSTM epilogue.
// Grid: 2048 flat blocks (64 m-tiles x 32 j-tiles after XCD swizzle),
// 512 threads (8 waves: wm in [0,4) x wn in [0,2)); per-wave 64x64 output.
// LDS (dynamic, 48 KiB): 2 slots x {A[256][32] | B[128][32]} bf16.
// 64B rows, 16B segs XOR-swizzled by (row>>1)&3 (both-sides involution:
// pre-swizzled global src for global_load_lds, swizzled ds_read addr).
// B LDS p-row rl holds physical n = ((rl>>4)&3)*1024 + j0 + (rl>>6)*16 + (rl&15)
// so acc[mi][ni] = gate ni of column j0 + wn*16 + cc.
// Per tile t: stage(t+1) (dist-1, slot^1) -> 8 ds_reads -> 16 MFMA ->
// __syncthreads (drains vmcnt; co-resident block hides the drain).
__global__ __launch_bounds__(512, 4)
void lstm_gemm(const unsigned short* __restrict__ A, const unsigned short* __restrict__ Bt,
               const float* __restrict__ c0, float* __restrict__ out) {
  extern __shared__ char smem[];  // 49152 bytes
  const int tid = threadIdx.x;
  const int wave = tid >> 6, lane = tid & 63;
  const int q = lane >> 4, cc = lane & 15;
  const int wm = wave >> 1, wn = wave & 1;

  // T1: bijective XCD swizzle (nwg=2048 % 8 == 0).
  const int bid = blockIdx.x;
  const int swz = (bid & 7) * 256 + (bid >> 3);
  const int m0 = (swz >> 5) * 256;
  const int j0 = (swz & 31) * 32;

  // Staging source offsets (bytes/lane): lane l covers LDS row
  // u*128 + wave*16 + (l>>2) (A; u=0,1) or wave*16 + (l>>2) (B),
  // 16B seg (l&3) pre-XOR'd with row bits 1-2.
  const int srow = lane >> 2;
  const int sseg = (lane & 3) ^ ((lane >> 3) & 3);
  uint32_t aoff[2], boff;
  #pragma unroll
  for (int u = 0; u < 2; ++u) {
    int rl = u * 128 + wave * 16 + srow;     // A LDS row 0..255
    aoff[u] = (((uint32_t)(m0 + rl) << 11) + (uint32_t)(sseg * 8)) * 2u;
  }
  {
    int rl = wave * 16 + srow;               // B LDS row 0..127
    int n = (((rl >> 4) & 3) << 10) + j0 + ((rl >> 6) << 4) + (rl & 15);
    boff = (((uint32_t)n << 11) + (uint32_t)(sseg * 8)) * 2u;
  }
  const char* Ab = (const char*)A;
  const char* Bb = (const char*)Bt;

  auto stageAB = [&](int tt) {
    const uint32_t so = (uint32_t)(tt & 1) * SLOT_BYTES;
    #pragma unroll
    for (int u = 0; u < 2; ++u) {
      uintptr_t l = (uintptr_t)(smem + so + u * 8192 + wave * 1024);
      __builtin_amdgcn_global_load_lds(
          (const __attribute__((address_space(1))) void*)(uintptr_t)(Ab + (aoff[u] + (uint32_t)tt * 64u)),
          (__attribute__((address_space(3))) void*)(uint32_t)l, 16, 0, 0);
    }
    uintptr_t l = (uintptr_t)(smem + so + 16384 + wave * 1024);
    __builtin_amdgcn_global_load_lds(
        (const __attribute__((address_space(1))) void*)(uintptr_t)(Bb + (boff + (uint32_t)tt * 64u)),
        (__attribute__((address_space(3))) void*)(uint32_t)l, 16, 0, 0);
  };

  f32x4 acc[4][4];
  #pragma unroll
  for (int a = 0; a < 4; ++a)
    #pragma unroll
    for (int b = 0; b < 4; ++b)
      acc[a][b] = f32x4{0.f, 0.f, 0.f, 0.f};

  // Frag-read base offsets (seg-swizzled by row bits 1-2, which come from cc).
  const uint32_t swzq = (uint32_t)((q ^ ((cc >> 1) & 3)) * 16);
  const uint32_t aRd = (uint32_t)((wm * 64 + cc) * 64) + swzq;
  const uint32_t bRd = 16384u + (uint32_t)((wn * 64 + cc) * 64) + swzq;

  // Prologue: stage tile 0; __syncthreads drains + publishes.
  stageAB(0);
  __syncthreads();

  for (int t = 0; t < NT; ++t) {
    const char* sb = smem + (t & 1) * SLOT_BYTES;
    if (t < NT - 1) stageAB(t + 1);
    bf16x8 af[4], bf[4];
    #pragma unroll
    for (int mi = 0; mi < 4; ++mi) af[mi] = *(const bf16x8*)(sb + aRd + mi * 1024);
    #pragma unroll
    for (int ni = 0; ni < 4; ++ni) bf[ni] = *(const bf16x8*)(sb + bRd + ni * 1024);
    __builtin_amdgcn_s_setprio(1);
    #pragma unroll
    for (int mi = 0; mi < 4; ++mi)
      #pragma unroll
      for (int ni = 0; ni < 4; ++ni)
        acc[mi][ni] = __builtin_amdgcn_mfma_f32_16x16x32_bf16(af[mi], bf[ni], acc[mi][ni], 0, 0, 0);
    __builtin_amdgcn_s_setprio(0);
    if (t < NT - 1) __syncthreads();  // drains vmcnt(0): tile t+1 landed
  }

  // Register-local fused epilogue: acc[mi][0..3] = i,f,g,o of (grow, gj).
  // C-layout: col = lane&15 (= cc), row = q*4 + r.
  const int gj = j0 + wn * 16 + cc;
  #pragma unroll
  for (int mi = 0; mi < 4; ++mi) {
    #pragma unroll
    for (int r = 0; r < 4; ++r) {
      int grow = m0 + wm * 64 + mi * 16 + q * 4 + r;
      float iv = fsig(acc[mi][0][r]);
      float fv = fsig(acc[mi][1][r]);
      float gv = ftanh_(acc[mi][2][r]);
      float ov = fsig(acc[mi][3][r]);
      float c0v = c0[(size_t)grow * DH + gj];
      float cv = fv * c0v + iv * gv;
      float hv = ov * ftanh_(cv);
      out[(size_t)grow * DH + gj] = hv;
      out[HC_ELEMS + (size_t)grow * DH + gj] = cv;
    }
  }
}

extern "C" void kernel_launch(void* const* d_in, const int* in_sizes, int n_in,
                              void* d_out, int out_size, void* d_ws, size_t ws_size,
                              hipStream_t stream) {
  const float* X  = (const float*)d_in[0];
  const float* h0 = (const float*)d_in[1];
  const float* c0 = (const float*)d_in[2];
  const float* U  = (const float*)d_in[3];
  const float* W  = (const float*)d_in[4];
  float* out = (float*)d_out;

  // ws layout: A_bf16 (16384x2048, 64MB) | Bt_bf16 (4096x2048, 16MB) = 80MB
  unsigned short* Abf = (unsigned short*)d_ws;
  unsigned short* Bt  = Abf + 33554432ull;

  static bool attr_set = false;
  if (!attr_set) {
    (void)hipFuncSetAttribute(reinterpret_cast<const void*>(lstm_gemm),
                              hipFuncAttributeMaxDynamicSharedMemorySize, 49152);
    attr_set = true;
  }

  prep<<<13312, 256, 0, stream>>>(X, h0, W, U, Abf, Bt);
  lstm_gemm<<<2048, 512, 49152, stream>>>(Abf, Bt, c0, out);
}